// Round 5
// baseline (980.699 us; speedup 1.0000x reference)
//
#include <hip/hip_runtime.h>

#define N_NODES 100000
#define N_EDGES 3200000
#define IN_CH   384
#define HID     128
#define SCAN_NBLK ((N_NODES + 1023) / 1024)   // 98
#define BKT_SHIFT 5
#define NBKT (N_NODES >> BKT_SHIFT)           // 3125 buckets x 32 nodes (exact)

static __device__ __forceinline__ unsigned short f2bf(float f) {
    unsigned u = __float_as_uint(f);
    unsigned r = (u + 0x7fffu + ((u >> 16) & 1u)) >> 16;   // RTN-even
    return (unsigned short)r;
}

// ---------------- degree count (in-degree, excl self-loop) ----------------
__global__ void k_count(const int* __restrict__ dst, unsigned* __restrict__ deg, int E4) {
    int i = blockIdx.x * blockDim.x + threadIdx.x;
    int stride = gridDim.x * blockDim.x;
    const int4* d4 = (const int4*)dst;
    for (; i < E4; i += stride) {
        int4 v = d4[i];
        atomicAdd(&deg[v.x], 1u);
        atomicAdd(&deg[v.y], 1u);
        atomicAdd(&deg[v.z], 1u);
        atomicAdd(&deg[v.w], 1u);
    }
}

__global__ void k_dis(const unsigned* __restrict__ deg, float* __restrict__ dis, int N) {
    int i = blockIdx.x * blockDim.x + threadIdx.x;
    if (i < N) dis[i] = rsqrtf((float)(deg[i] + 1u));  // +1 self-loop
}

// ---------------- two-level exclusive scan: deg -> rowptr ----------------
__global__ __launch_bounds__(256) void k_scan1(const unsigned* __restrict__ deg,
                                               unsigned* __restrict__ rowptr,
                                               unsigned* __restrict__ bsum, int N) {
    __shared__ unsigned s[256];
    const int t = threadIdx.x;
    const int base = blockIdx.x * 1024 + t * 4;
    unsigned v[4], sum = 0;
#pragma unroll
    for (int i = 0; i < 4; i++) {
        v[i] = (base + i < N) ? deg[base + i] : 0u;
        sum += v[i];
    }
    s[t] = sum;
    __syncthreads();
    for (int off = 1; off < 256; off <<= 1) {
        unsigned x = s[t];
        unsigned y = (t >= off) ? s[t - off] : 0u;
        __syncthreads();
        s[t] = x + y;
        __syncthreads();
    }
    unsigned ex = s[t] - sum;
    unsigned run = 0;
#pragma unroll
    for (int i = 0; i < 4; i++) {
        if (base + i < N) rowptr[base + i] = ex + run;
        run += v[i];
    }
    if (t == 255) bsum[blockIdx.x] = s[255];
}

__global__ __launch_bounds__(128) void k_scan2(unsigned* __restrict__ bsum, int nb) {
    __shared__ unsigned s[128];
    const int t = threadIdx.x;
    unsigned orig = (t < nb) ? bsum[t] : 0u;
    s[t] = orig;
    __syncthreads();
    for (int off = 1; off < 128; off <<= 1) {
        unsigned x = s[t];
        unsigned y = (t >= off) ? s[t - off] : 0u;
        __syncthreads();
        s[t] = x + y;
        __syncthreads();
    }
    if (t < nb) bsum[t] = s[t] - orig;
}

__global__ __launch_bounds__(256) void k_scan3(unsigned* __restrict__ rowptr,
                                               const unsigned* __restrict__ bsum, int N, int E) {
    const int t = threadIdx.x;
    const int base = blockIdx.x * 1024 + t * 4;
    unsigned add = bsum[blockIdx.x];
#pragma unroll
    for (int i = 0; i < 4; i++)
        if (base + i < N) rowptr[base + i] += add;
    if (blockIdx.x == 0 && t == 0) rowptr[N] = (unsigned)E;
}

// ---------------- bucket cursors: bcursor[b] = rowptr[b*32] ----------------
__global__ void k_bcur(const unsigned* __restrict__ rowptr, unsigned* __restrict__ bcursor, int nb) {
    int b = blockIdx.x * blockDim.x + threadIdx.x;
    if (b < nb) bcursor[b] = rowptr[b << BKT_SHIFT];
}

// ---------------- pass B: bin (src,dst) pairs by dst bucket ----------------
__global__ void k_bin(const int* __restrict__ src, const int* __restrict__ dst,
                      unsigned* __restrict__ bcursor, int2* __restrict__ ebuf, int E4) {
    int i = blockIdx.x * blockDim.x + threadIdx.x;
    int stride = gridDim.x * blockDim.x;
    const int4* s4 = (const int4*)src;
    const int4* d4 = (const int4*)dst;
    for (; i < E4; i += stride) {
        int4 sv = s4[i];
        int4 dv = d4[i];
        unsigned p0 = atomicAdd(&bcursor[dv.x >> BKT_SHIFT], 1u);
        ebuf[p0] = make_int2(sv.x, dv.x);
        unsigned p1 = atomicAdd(&bcursor[dv.y >> BKT_SHIFT], 1u);
        ebuf[p1] = make_int2(sv.y, dv.y);
        unsigned p2 = atomicAdd(&bcursor[dv.z >> BKT_SHIFT], 1u);
        ebuf[p2] = make_int2(sv.z, dv.z);
        unsigned p3 = atomicAdd(&bcursor[dv.w >> BKT_SHIFT], 1u);
        ebuf[p3] = make_int2(sv.w, dv.w);
    }
}

// ---------------- pass C: localized CSR fill from binned edges ----------------
__global__ void k_fill2(const int2* __restrict__ ebuf, const unsigned* __restrict__ rowptr,
                        unsigned* __restrict__ cursor, int* __restrict__ csr_src, int E2) {
    int i = blockIdx.x * blockDim.x + threadIdx.x;
    int stride = gridDim.x * blockDim.x;
    const int4* e4 = (const int4*)ebuf;   // 2 edges per int4
    for (; i < E2; i += stride) {
        int4 ev = e4[i];
        unsigned p0 = rowptr[ev.y] + atomicAdd(&cursor[ev.y], 1u);
        csr_src[p0] = ev.x;
        unsigned p1 = rowptr[ev.w] + atomicAdd(&cursor[ev.w], 1u);
        csr_src[p1] = ev.z;
    }
}

// ---------------- fp32 GEMM -> bf16 out: C[M,128] = A[M,K] @ B[K,128] ----------------
__global__ __launch_bounds__(256) void k_gemm(const float* __restrict__ A,
                                              const float* __restrict__ B,
                                              unsigned short* __restrict__ C, int M, int K) {
    __shared__ float As[16][132];   // transposed: As[k][row]
    __shared__ float Bs[16][132];
    const int tid = threadIdx.x;
    const int tx = tid & 15;
    const int ty = tid >> 4;
    const int row0 = blockIdx.x * 128;

    float acc[2][2][4][4];
#pragma unroll
    for (int p = 0; p < 2; p++)
#pragma unroll
        for (int q = 0; q < 2; q++)
#pragma unroll
            for (int i = 0; i < 4; i++)
#pragma unroll
                for (int j = 0; j < 4; j++) acc[p][q][i][j] = 0.f;

    for (int k0 = 0; k0 < K; k0 += 16) {
#pragma unroll
        for (int t = 0; t < 2; t++) {
            int f4 = tid + t * 256;
            int r = f4 >> 2;
            int c4 = (f4 & 3) * 4;
            int ar = row0 + r;
            float4 av = make_float4(0.f, 0.f, 0.f, 0.f);
            if (ar < M) av = *reinterpret_cast<const float4*>(&A[(size_t)ar * K + k0 + c4]);
            As[c4 + 0][r] = av.x;
            As[c4 + 1][r] = av.y;
            As[c4 + 2][r] = av.z;
            As[c4 + 3][r] = av.w;
        }
#pragma unroll
        for (int t = 0; t < 2; t++) {
            int f4 = tid + t * 256;
            int br = f4 >> 5;
            int bc = (f4 & 31) * 4;
            *reinterpret_cast<float4*>(&Bs[br][bc]) =
                *reinterpret_cast<const float4*>(&B[(size_t)(k0 + br) * 128 + bc]);
        }
        __syncthreads();
#pragma unroll
        for (int kk = 0; kk < 16; kk++) {
            float4 a0 = *reinterpret_cast<const float4*>(&As[kk][ty * 4]);
            float4 a1 = *reinterpret_cast<const float4*>(&As[kk][64 + ty * 4]);
            float4 b0 = *reinterpret_cast<const float4*>(&Bs[kk][tx * 4]);
            float4 b1 = *reinterpret_cast<const float4*>(&Bs[kk][64 + tx * 4]);
            float af[2][4] = {{a0.x, a0.y, a0.z, a0.w}, {a1.x, a1.y, a1.z, a1.w}};
            float bf[2][4] = {{b0.x, b0.y, b0.z, b0.w}, {b1.x, b1.y, b1.z, b1.w}};
#pragma unroll
            for (int p = 0; p < 2; p++)
#pragma unroll
                for (int q = 0; q < 2; q++)
#pragma unroll
                    for (int i = 0; i < 4; i++)
#pragma unroll
                        for (int j = 0; j < 4; j++)
                            acc[p][q][i][j] = fmaf(af[p][i], bf[q][j], acc[p][q][i][j]);
        }
        __syncthreads();
    }
#pragma unroll
    for (int p = 0; p < 2; p++)
#pragma unroll
        for (int i = 0; i < 4; i++) {
            int r = row0 + p * 64 + ty * 4 + i;
            if (r < M) {
#pragma unroll
                for (int q = 0; q < 2; q++) {
                    ushort4 cv;
                    cv.x = f2bf(acc[p][q][i][0]);
                    cv.y = f2bf(acc[p][q][i][1]);
                    cv.z = f2bf(acc[p][q][i][2]);
                    cv.w = f2bf(acc[p][q][i][3]);
                    *reinterpret_cast<ushort4*>(&C[(size_t)r * 128 + q * 64 + tx * 4]) = cv;
                }
            }
        }
}

// ---------------- aggregate: one wave per dst node, bf16 gather, unrolled x8 ----------------
__global__ __launch_bounds__(256) void k_aggregate(const unsigned short* __restrict__ h,
                                                   const int* __restrict__ csr_src,
                                                   const unsigned* __restrict__ rowptr,
                                                   const float* __restrict__ dis,
                                                   const float* __restrict__ bias,
                                                   float* __restrict__ out, int N, int relu) {
    const int wid = (int)((blockIdx.x * (blockDim.x >> 6)) + (threadIdx.x >> 6));
    const int d = __builtin_amdgcn_readfirstlane(wid);   // wave-uniform -> SGPR
    if (d >= N) return;
    const int lane = threadIdx.x & 63;
    const unsigned beg = rowptr[d], end = rowptr[d + 1];
    const float dd = dis[d];
    const unsigned* h1 = reinterpret_cast<const unsigned*>(h);  // 64 dwords/row = 2 bf16 each

    unsigned hv = h1[(size_t)d * 64 + lane];
    float ax = dd * __uint_as_float(hv << 16);           // ch 2*lane
    float ay = dd * __uint_as_float(hv & 0xffff0000u);   // ch 2*lane+1

    unsigned e = beg;
    for (; e + 8 <= end; e += 8) {
        int s[8];
        float w[8];
        unsigned v[8];
#pragma unroll
        for (int u = 0; u < 8; u++) s[u] = csr_src[e + u];
#pragma unroll
        for (int u = 0; u < 8; u++) w[u] = dis[s[u]];
#pragma unroll
        for (int u = 0; u < 8; u++) v[u] = h1[(size_t)s[u] * 64 + lane];
#pragma unroll
        for (int u = 0; u < 8; u++) {
            ax = fmaf(w[u], __uint_as_float(v[u] << 16), ax);
            ay = fmaf(w[u], __uint_as_float(v[u] & 0xffff0000u), ay);
        }
    }
    for (; e < end; e++) {
        int s0 = csr_src[e];
        float w0 = dis[s0];
        unsigned v0 = h1[(size_t)s0 * 64 + lane];
        ax = fmaf(w0, __uint_as_float(v0 << 16), ax);
        ay = fmaf(w0, __uint_as_float(v0 & 0xffff0000u), ay);
    }
    float2 bv = reinterpret_cast<const float2*>(bias)[lane];
    float r0 = fmaf(dd, ax, bv.x);
    float r1 = fmaf(dd, ay, bv.y);
    if (relu) { r0 = fmaxf(r0, 0.f); r1 = fmaxf(r1, 0.f); }
    reinterpret_cast<float2*>(out)[(size_t)d * 64 + lane] = make_float2(r0, r1);
}

extern "C" void kernel_launch(void* const* d_in, const int* in_sizes, int n_in,
                              void* d_out, int out_size, void* d_ws, size_t ws_size,
                              hipStream_t stream) {
    const float* x  = (const float*)d_in[0];
    const int*   ei = (const int*)d_in[1];
    const float* W1 = (const float*)d_in[2];
    const float* b1 = (const float*)d_in[3];
    const float* W2 = (const float*)d_in[4];
    const float* b2 = (const float*)d_in[5];
    const int* src = ei;             // edge_index[0]
    const int* dst = ei + N_EDGES;   // edge_index[1]
    float* out = (float*)d_out;

    char* ws = (char*)d_ws;
    unsigned*       deg     = (unsigned*)ws;                              // 400000 (reused as cursor)
    float*          dis     = (float*)(ws + 400000);                      // 400000
    unsigned*       rowptr  = (unsigned*)(ws + 800000);                   // 400004 (+pad)
    unsigned*       bsum    = (unsigned*)(ws + 1200512);                  // 4 KB
    unsigned*       bcursor = (unsigned*)(ws + 1204608);                  // 12.5 KB (+pad)
    int*            csr     = (int*)(ws + 1217152);                       // 12.8 MB
    int2*           ebuf    = (int2*)(ws + 1217152 + 12800000);           // 25.6 MB
    unsigned short* hbf     = (unsigned short*)(ws + 1217152 + 12800000 + 25600000);  // 25.6 MB
    float*          a       = (float*)(ws + 1217152 + 12800000 + 25600000 + 25600000); // 51.2 MB

    // ---- degrees + normalization ----
    hipMemsetAsync(deg, 0, N_NODES * sizeof(unsigned), stream);
    k_count<<<2048, 256, 0, stream>>>(dst, deg, N_EDGES / 4);
    k_dis<<<(N_NODES + 255) / 256, 256, 0, stream>>>(deg, dis, N_NODES);

    // ---- CSR by destination (binned two-phase build) ----
    k_scan1<<<SCAN_NBLK, 256, 0, stream>>>(deg, rowptr, bsum, N_NODES);
    k_scan2<<<1, 128, 0, stream>>>(bsum, SCAN_NBLK);
    k_scan3<<<SCAN_NBLK, 256, 0, stream>>>(rowptr, bsum, N_NODES, N_EDGES);
    k_bcur<<<(NBKT + 255) / 256, 256, 0, stream>>>(rowptr, bcursor, NBKT);
    k_bin<<<2048, 256, 0, stream>>>(src, dst, bcursor, ebuf, N_EDGES / 4);
    hipMemsetAsync(deg, 0, N_NODES * sizeof(unsigned), stream);   // deg -> cursor
    k_fill2<<<2048, 256, 0, stream>>>(ebuf, rowptr, deg, csr, N_EDGES / 2);

    // ---- layer 1 ----
    k_gemm<<<(N_NODES + 127) / 128, 256, 0, stream>>>(x, W1, hbf, N_NODES, IN_CH);
    k_aggregate<<<(N_NODES * 64 + 255) / 256, 256, 0, stream>>>(hbf, csr, rowptr, dis, b1, a, N_NODES, 1);

    // ---- layer 2 ----
    k_gemm<<<(N_NODES + 127) / 128, 256, 0, stream>>>(a, W2, hbf, N_NODES, HID);
    k_aggregate<<<(N_NODES * 64 + 255) / 256, 256, 0, stream>>>(hbf, csr, rowptr, dis, b2, out, N_NODES, 0);
}

// Round 6
// 681.009 us; speedup vs baseline: 1.4401x; 1.4401x over previous
//
#include <hip/hip_runtime.h>

#define N_NODES 100000
#define N_EDGES 3200000
#define IN_CH   384
#define HID     128
#define SCAN_NBLK ((N_NODES + 1023) / 1024)   // 98
#define BKT_SHIFT 7
#define NBKT ((N_NODES + 127) >> 7)           // 782 buckets x 128 nodes
#define BINBLK 256                            // blocks in binning pass
#define CHUNK4 (N_EDGES / 4 / BINBLK)         // 3125 int4 per block (exact)

static __device__ __forceinline__ unsigned short f2bf(float f) {
    unsigned u = __float_as_uint(f);
    unsigned r = (u + 0x7fffu + ((u >> 16) & 1u)) >> 16;   // RTN-even
    return (unsigned short)r;
}

// ---------------- degree count (in-degree, excl self-loop) ----------------
__global__ void k_count(const int* __restrict__ dst, unsigned* __restrict__ deg, int E4) {
    int i = blockIdx.x * blockDim.x + threadIdx.x;
    int stride = gridDim.x * blockDim.x;
    const int4* d4 = (const int4*)dst;
    for (; i < E4; i += stride) {
        int4 v = d4[i];
        atomicAdd(&deg[v.x], 1u);
        atomicAdd(&deg[v.y], 1u);
        atomicAdd(&deg[v.z], 1u);
        atomicAdd(&deg[v.w], 1u);
    }
}

__global__ void k_dis(const unsigned* __restrict__ deg, float* __restrict__ dis, int N) {
    int i = blockIdx.x * blockDim.x + threadIdx.x;
    if (i < N) dis[i] = rsqrtf((float)(deg[i] + 1u));  // +1 self-loop
}

// ---------------- two-level exclusive scan: deg -> rowptr ----------------
__global__ __launch_bounds__(256) void k_scan1(const unsigned* __restrict__ deg,
                                               unsigned* __restrict__ rowptr,
                                               unsigned* __restrict__ bsum, int N) {
    __shared__ unsigned s[256];
    const int t = threadIdx.x;
    const int base = blockIdx.x * 1024 + t * 4;
    unsigned v[4], sum = 0;
#pragma unroll
    for (int i = 0; i < 4; i++) {
        v[i] = (base + i < N) ? deg[base + i] : 0u;
        sum += v[i];
    }
    s[t] = sum;
    __syncthreads();
    for (int off = 1; off < 256; off <<= 1) {
        unsigned x = s[t];
        unsigned y = (t >= off) ? s[t - off] : 0u;
        __syncthreads();
        s[t] = x + y;
        __syncthreads();
    }
    unsigned ex = s[t] - sum;
    unsigned run = 0;
#pragma unroll
    for (int i = 0; i < 4; i++) {
        if (base + i < N) rowptr[base + i] = ex + run;
        run += v[i];
    }
    if (t == 255) bsum[blockIdx.x] = s[255];
}

__global__ __launch_bounds__(128) void k_scan2(unsigned* __restrict__ bsum, int nb) {
    __shared__ unsigned s[128];
    const int t = threadIdx.x;
    unsigned orig = (t < nb) ? bsum[t] : 0u;
    s[t] = orig;
    __syncthreads();
    for (int off = 1; off < 128; off <<= 1) {
        unsigned x = s[t];
        unsigned y = (t >= off) ? s[t - off] : 0u;
        __syncthreads();
        s[t] = x + y;
        __syncthreads();
    }
    if (t < nb) bsum[t] = s[t] - orig;
}

__global__ __launch_bounds__(256) void k_scan3(unsigned* __restrict__ rowptr,
                                               const unsigned* __restrict__ bsum, int N, int E) {
    const int t = threadIdx.x;
    const int base = blockIdx.x * 1024 + t * 4;
    unsigned add = bsum[blockIdx.x];
#pragma unroll
    for (int i = 0; i < 4; i++)
        if (base + i < N) rowptr[base + i] += add;
    if (blockIdx.x == 0 && t == 0) rowptr[N] = (unsigned)E;
}

// ---------------- counting sort by 128-node bucket, pass 1: per-block LDS histogram ----------------
__global__ __launch_bounds__(256) void k_bhist(const int* __restrict__ dst,
                                               unsigned* __restrict__ hist) {
    __shared__ unsigned lh[NBKT];
    for (int b = threadIdx.x; b < NBKT; b += 256) lh[b] = 0;
    __syncthreads();
    const int4* d4 = (const int4*)dst;
    const int base = blockIdx.x * CHUNK4;
    for (int i = threadIdx.x; i < CHUNK4; i += 256) {
        int4 v = d4[base + i];
        atomicAdd(&lh[v.x >> BKT_SHIFT], 1u);
        atomicAdd(&lh[v.y >> BKT_SHIFT], 1u);
        atomicAdd(&lh[v.z >> BKT_SHIFT], 1u);
        atomicAdd(&lh[v.w >> BKT_SHIFT], 1u);
    }
    __syncthreads();
    for (int b = threadIdx.x; b < NBKT; b += 256) hist[b * BINBLK + blockIdx.x] = lh[b];
}

// pass 2: one block per bin scans its 256 block-counts -> global ebuf offsets
__global__ __launch_bounds__(256) void k_bscan(unsigned* __restrict__ hist,
                                               const unsigned* __restrict__ rowptr) {
    __shared__ unsigned s[256];
    const int b = blockIdx.x, t = threadIdx.x;
    unsigned v = hist[b * BINBLK + t];
    s[t] = v;
    __syncthreads();
    for (int off = 1; off < 256; off <<= 1) {
        unsigned x = s[t];
        unsigned y = (t >= off) ? s[t - off] : 0u;
        __syncthreads();
        s[t] = x + y;
        __syncthreads();
    }
    hist[b * BINBLK + t] = rowptr[b << BKT_SHIFT] + s[t] - v;   // exclusive + bucket base
}

// pass 3: scatter (src,dst) into bucket-grouped ebuf; LDS cursors, block-private ranges
__global__ __launch_bounds__(256) void k_bscat(const int* __restrict__ src,
                                               const int* __restrict__ dst,
                                               const unsigned* __restrict__ hist,
                                               int2* __restrict__ ebuf) {
    __shared__ unsigned lcur[NBKT];
    for (int b = threadIdx.x; b < NBKT; b += 256) lcur[b] = hist[b * BINBLK + blockIdx.x];
    __syncthreads();
    const int4* s4 = (const int4*)src;
    const int4* d4 = (const int4*)dst;
    const int base = blockIdx.x * CHUNK4;
    for (int i = threadIdx.x; i < CHUNK4; i += 256) {
        int4 sv = s4[base + i];
        int4 dv = d4[base + i];
        unsigned p;
        p = atomicAdd(&lcur[dv.x >> BKT_SHIFT], 1u); ebuf[p] = make_int2(sv.x, dv.x);
        p = atomicAdd(&lcur[dv.y >> BKT_SHIFT], 1u); ebuf[p] = make_int2(sv.y, dv.y);
        p = atomicAdd(&lcur[dv.z >> BKT_SHIFT], 1u); ebuf[p] = make_int2(sv.z, dv.z);
        p = atomicAdd(&lcur[dv.w >> BKT_SHIFT], 1u); ebuf[p] = make_int2(sv.w, dv.w);
    }
}

// pass 4: one block per bucket; per-node LDS cursors; csr writes land in a 16 KB window
__global__ __launch_bounds__(256) void k_fill3(const int2* __restrict__ ebuf,
                                               const unsigned* __restrict__ rowptr,
                                               int* __restrict__ csr, int N) {
    __shared__ unsigned lcur[1 << BKT_SHIFT];
    const int b = blockIdx.x, t = threadIdx.x;
    if (t < (1 << BKT_SHIFT)) lcur[t] = 0;
    __syncthreads();
    const int n0 = b << BKT_SHIFT;
    const int n1 = min(n0 + (1 << BKT_SHIFT), N);
    const unsigned beg = rowptr[n0];
    const unsigned end = rowptr[n1];
    for (unsigned i = beg + t; i < end; i += 256) {
        int2 e = ebuf[i];
        unsigned pos = rowptr[e.y] + atomicAdd(&lcur[e.y - n0], 1u);
        csr[pos] = e.x;
    }
}

// ---------------- fp32 GEMM -> bf16 out: C[M,128] = A[M,K] @ B[K,128] ----------------
__global__ __launch_bounds__(256) void k_gemm(const float* __restrict__ A,
                                              const float* __restrict__ B,
                                              unsigned short* __restrict__ C, int M, int K) {
    __shared__ float As[16][132];   // transposed: As[k][row]
    __shared__ float Bs[16][132];
    const int tid = threadIdx.x;
    const int tx = tid & 15;
    const int ty = tid >> 4;
    const int row0 = blockIdx.x * 128;

    float acc[2][2][4][4];
#pragma unroll
    for (int p = 0; p < 2; p++)
#pragma unroll
        for (int q = 0; q < 2; q++)
#pragma unroll
            for (int i = 0; i < 4; i++)
#pragma unroll
                for (int j = 0; j < 4; j++) acc[p][q][i][j] = 0.f;

    for (int k0 = 0; k0 < K; k0 += 16) {
#pragma unroll
        for (int t = 0; t < 2; t++) {
            int f4 = tid + t * 256;
            int r = f4 >> 2;
            int c4 = (f4 & 3) * 4;
            int ar = row0 + r;
            float4 av = make_float4(0.f, 0.f, 0.f, 0.f);
            if (ar < M) av = *reinterpret_cast<const float4*>(&A[(size_t)ar * K + k0 + c4]);
            As[c4 + 0][r] = av.x;
            As[c4 + 1][r] = av.y;
            As[c4 + 2][r] = av.z;
            As[c4 + 3][r] = av.w;
        }
#pragma unroll
        for (int t = 0; t < 2; t++) {
            int f4 = tid + t * 256;
            int br = f4 >> 5;
            int bc = (f4 & 31) * 4;
            *reinterpret_cast<float4*>(&Bs[br][bc]) =
                *reinterpret_cast<const float4*>(&B[(size_t)(k0 + br) * 128 + bc]);
        }
        __syncthreads();
#pragma unroll
        for (int kk = 0; kk < 16; kk++) {
            float4 a0 = *reinterpret_cast<const float4*>(&As[kk][ty * 4]);
            float4 a1 = *reinterpret_cast<const float4*>(&As[kk][64 + ty * 4]);
            float4 b0 = *reinterpret_cast<const float4*>(&Bs[kk][tx * 4]);
            float4 b1 = *reinterpret_cast<const float4*>(&Bs[kk][64 + tx * 4]);
            float af[2][4] = {{a0.x, a0.y, a0.z, a0.w}, {a1.x, a1.y, a1.z, a1.w}};
            float bf[2][4] = {{b0.x, b0.y, b0.z, b0.w}, {b1.x, b1.y, b1.z, b1.w}};
#pragma unroll
            for (int p = 0; p < 2; p++)
#pragma unroll
                for (int q = 0; q < 2; q++)
#pragma unroll
                    for (int i = 0; i < 4; i++)
#pragma unroll
                        for (int j = 0; j < 4; j++)
                            acc[p][q][i][j] = fmaf(af[p][i], bf[q][j], acc[p][q][i][j]);
        }
        __syncthreads();
    }
#pragma unroll
    for (int p = 0; p < 2; p++)
#pragma unroll
        for (int i = 0; i < 4; i++) {
            int r = row0 + p * 64 + ty * 4 + i;
            if (r < M) {
#pragma unroll
                for (int q = 0; q < 2; q++) {
                    ushort4 cv;
                    cv.x = f2bf(acc[p][q][i][0]);
                    cv.y = f2bf(acc[p][q][i][1]);
                    cv.z = f2bf(acc[p][q][i][2]);
                    cv.w = f2bf(acc[p][q][i][3]);
                    *reinterpret_cast<ushort4*>(&C[(size_t)r * 128 + q * 64 + tx * 4]) = cv;
                }
            }
        }
}

// ---------------- aggregate: one wave per dst node, bf16 gather, unrolled x8 ----------------
__global__ __launch_bounds__(256) void k_aggregate(const unsigned short* __restrict__ h,
                                                   const int* __restrict__ csr_src,
                                                   const unsigned* __restrict__ rowptr,
                                                   const float* __restrict__ dis,
                                                   const float* __restrict__ bias,
                                                   float* __restrict__ out, int N, int relu) {
    const int wid = (int)((blockIdx.x * (blockDim.x >> 6)) + (threadIdx.x >> 6));
    const int d = __builtin_amdgcn_readfirstlane(wid);   // wave-uniform -> SGPR
    if (d >= N) return;
    const int lane = threadIdx.x & 63;
    const unsigned beg = rowptr[d], end = rowptr[d + 1];
    const float dd = dis[d];
    const unsigned* h1 = reinterpret_cast<const unsigned*>(h);  // 64 dwords/row = 2 bf16 each

    unsigned hv = h1[(size_t)d * 64 + lane];
    float ax = dd * __uint_as_float(hv << 16);           // ch 2*lane
    float ay = dd * __uint_as_float(hv & 0xffff0000u);   // ch 2*lane+1

    unsigned e = beg;
    for (; e + 8 <= end; e += 8) {
        int s[8];
        float w[8];
        unsigned v[8];
#pragma unroll
        for (int u = 0; u < 8; u++) s[u] = csr_src[e + u];
#pragma unroll
        for (int u = 0; u < 8; u++) w[u] = dis[s[u]];
#pragma unroll
        for (int u = 0; u < 8; u++) v[u] = h1[(size_t)s[u] * 64 + lane];
#pragma unroll
        for (int u = 0; u < 8; u++) {
            ax = fmaf(w[u], __uint_as_float(v[u] << 16), ax);
            ay = fmaf(w[u], __uint_as_float(v[u] & 0xffff0000u), ay);
        }
    }
    for (; e < end; e++) {
        int s0 = csr_src[e];
        float w0 = dis[s0];
        unsigned v0 = h1[(size_t)s0 * 64 + lane];
        ax = fmaf(w0, __uint_as_float(v0 << 16), ax);
        ay = fmaf(w0, __uint_as_float(v0 & 0xffff0000u), ay);
    }
    float2 bv = reinterpret_cast<const float2*>(bias)[lane];
    float r0 = fmaf(dd, ax, bv.x);
    float r1 = fmaf(dd, ay, bv.y);
    if (relu) { r0 = fmaxf(r0, 0.f); r1 = fmaxf(r1, 0.f); }
    reinterpret_cast<float2*>(out)[(size_t)d * 64 + lane] = make_float2(r0, r1);
}

extern "C" void kernel_launch(void* const* d_in, const int* in_sizes, int n_in,
                              void* d_out, int out_size, void* d_ws, size_t ws_size,
                              hipStream_t stream) {
    const float* x  = (const float*)d_in[0];
    const int*   ei = (const int*)d_in[1];
    const float* W1 = (const float*)d_in[2];
    const float* b1 = (const float*)d_in[3];
    const float* W2 = (const float*)d_in[4];
    const float* b2 = (const float*)d_in[5];
    const int* src = ei;             // edge_index[0]
    const int* dst = ei + N_EDGES;   // edge_index[1]
    float* out = (float*)d_out;

    char* ws = (char*)d_ws;
    unsigned*       deg    = (unsigned*)ws;                               // 400000
    float*          dis    = (float*)(ws + 400000);                       // 400000
    unsigned*       rowptr = (unsigned*)(ws + 800000);                    // 400004 (+pad)
    unsigned*       bsum   = (unsigned*)(ws + 1200512);                   // 4 KB
    int*            csr    = (int*)(ws + 1204608);                        // 12.8 MB
    int2*           ebuf   = (int2*)(ws + 1204608 + 12800000);            // 25.6 MB
    unsigned short* hbf    = (unsigned short*)(ws + 1204608 + 12800000 + 25600000);   // 25.6 MB
    float*          a      = (float*)(ws + 1204608 + 12800000 + 25600000 + 25600000); // 51.2 MB
    unsigned*       hist   = (unsigned*)a;   // 800 KB, aliases 'a' (dead before layer 1)

    // ---- degrees + normalization ----
    hipMemsetAsync(deg, 0, N_NODES * sizeof(unsigned), stream);
    k_count<<<2048, 256, 0, stream>>>(dst, deg, N_EDGES / 4);
    k_dis<<<(N_NODES + 255) / 256, 256, 0, stream>>>(deg, dis, N_NODES);

    // ---- rowptr = exclusive scan of deg ----
    k_scan1<<<SCAN_NBLK, 256, 0, stream>>>(deg, rowptr, bsum, N_NODES);
    k_scan2<<<1, 128, 0, stream>>>(bsum, SCAN_NBLK);
    k_scan3<<<SCAN_NBLK, 256, 0, stream>>>(rowptr, bsum, N_NODES, N_EDGES);

    // ---- CSR build: block-local counting sort by 128-node bucket ----
    k_bhist<<<BINBLK, 256, 0, stream>>>(dst, hist);
    k_bscan<<<NBKT, 256, 0, stream>>>(hist, rowptr);
    k_bscat<<<BINBLK, 256, 0, stream>>>(src, dst, hist, ebuf);
    k_fill3<<<NBKT, 256, 0, stream>>>(ebuf, rowptr, csr, N_NODES);

    // ---- layer 1 ----
    k_gemm<<<(N_NODES + 127) / 128, 256, 0, stream>>>(x, W1, hbf, N_NODES, IN_CH);
    k_aggregate<<<(N_NODES * 64 + 255) / 256, 256, 0, stream>>>(hbf, csr, rowptr, dis, b1, a, N_NODES, 1);

    // ---- layer 2 ----
    k_gemm<<<(N_NODES + 127) / 128, 256, 0, stream>>>(a, W2, hbf, N_NODES, HID);
    k_aggregate<<<(N_NODES * 64 + 255) / 256, 256, 0, stream>>>(hbf, csr, rowptr, dis, b2, out, N_NODES, 0);
}

// Round 7
// 569.733 us; speedup vs baseline: 1.7213x; 1.1953x over previous
//
#include <hip/hip_runtime.h>

#define N_NODES 100000
#define N_EDGES 3200000
#define IN_CH   384
#define HID     128
#define SCAN_NBLK ((N_NODES + 1023) / 1024)   // 98
#define BKT_SHIFT 7
#define NBKT ((N_NODES + 127) >> 7)           // 782 buckets x 128 nodes
#define BINBLK 256                            // blocks in binning pass
#define CHUNK4 (N_EDGES / 4 / BINBLK)         // 3125 int4 per block (exact)

typedef __attribute__((ext_vector_type(8))) short          bf16x8;
typedef __attribute__((ext_vector_type(8))) unsigned short u16x8;
typedef __attribute__((ext_vector_type(4))) float          f32x4;

static __device__ __forceinline__ unsigned short f2bf(float f) {
    unsigned u = __float_as_uint(f);
    unsigned r = (u + 0x7fffu + ((u >> 16) & 1u)) >> 16;   // RTN-even
    return (unsigned short)r;
}

// ---------------- degree count ----------------
__global__ void k_count(const int* __restrict__ dst, unsigned* __restrict__ deg, int E4) {
    int i = blockIdx.x * blockDim.x + threadIdx.x;
    int stride = gridDim.x * blockDim.x;
    const int4* d4 = (const int4*)dst;
    for (; i < E4; i += stride) {
        int4 v = d4[i];
        atomicAdd(&deg[v.x], 1u);
        atomicAdd(&deg[v.y], 1u);
        atomicAdd(&deg[v.z], 1u);
        atomicAdd(&deg[v.w], 1u);
    }
}

__global__ void k_dis(const unsigned* __restrict__ deg, float* __restrict__ dis, int N) {
    int i = blockIdx.x * blockDim.x + threadIdx.x;
    if (i < N) dis[i] = rsqrtf((float)(deg[i] + 1u));  // +1 self-loop
}

// ---------------- W -> transposed bf16: Wt[n][k] ----------------
__global__ void k_wt(const float* __restrict__ W, unsigned short* __restrict__ Wt, int K) {
    int i = blockIdx.x * blockDim.x + threadIdx.x;
    if (i < K * 128) {
        int k = i >> 7, n = i & 127;
        Wt[(size_t)n * K + k] = f2bf(W[i]);
    }
}

// ---------------- two-level exclusive scan: deg -> rowptr ----------------
__global__ __launch_bounds__(256) void k_scan1(const unsigned* __restrict__ deg,
                                               unsigned* __restrict__ rowptr,
                                               unsigned* __restrict__ bsum, int N) {
    __shared__ unsigned s[256];
    const int t = threadIdx.x;
    const int base = blockIdx.x * 1024 + t * 4;
    unsigned v[4], sum = 0;
#pragma unroll
    for (int i = 0; i < 4; i++) {
        v[i] = (base + i < N) ? deg[base + i] : 0u;
        sum += v[i];
    }
    s[t] = sum;
    __syncthreads();
    for (int off = 1; off < 256; off <<= 1) {
        unsigned x = s[t];
        unsigned y = (t >= off) ? s[t - off] : 0u;
        __syncthreads();
        s[t] = x + y;
        __syncthreads();
    }
    unsigned ex = s[t] - sum;
    unsigned run = 0;
#pragma unroll
    for (int i = 0; i < 4; i++) {
        if (base + i < N) rowptr[base + i] = ex + run;
        run += v[i];
    }
    if (t == 255) bsum[blockIdx.x] = s[255];
}

__global__ __launch_bounds__(128) void k_scan2(unsigned* __restrict__ bsum, int nb) {
    __shared__ unsigned s[128];
    const int t = threadIdx.x;
    unsigned orig = (t < nb) ? bsum[t] : 0u;
    s[t] = orig;
    __syncthreads();
    for (int off = 1; off < 128; off <<= 1) {
        unsigned x = s[t];
        unsigned y = (t >= off) ? s[t - off] : 0u;
        __syncthreads();
        s[t] = x + y;
        __syncthreads();
    }
    if (t < nb) bsum[t] = s[t] - orig;
}

__global__ __launch_bounds__(256) void k_scan3(unsigned* __restrict__ rowptr,
                                               const unsigned* __restrict__ bsum, int N, int E) {
    const int t = threadIdx.x;
    const int base = blockIdx.x * 1024 + t * 4;
    unsigned add = bsum[blockIdx.x];
#pragma unroll
    for (int i = 0; i < 4; i++)
        if (base + i < N) rowptr[base + i] += add;
    if (blockIdx.x == 0 && t == 0) rowptr[N] = (unsigned)E;
}

// ---------------- counting sort by 128-node bucket ----------------
__global__ __launch_bounds__(256) void k_bhist(const int* __restrict__ dst,
                                               unsigned* __restrict__ hist) {
    __shared__ unsigned lh[NBKT];
    for (int b = threadIdx.x; b < NBKT; b += 256) lh[b] = 0;
    __syncthreads();
    const int4* d4 = (const int4*)dst;
    const int base = blockIdx.x * CHUNK4;
    for (int i = threadIdx.x; i < CHUNK4; i += 256) {
        int4 v = d4[base + i];
        atomicAdd(&lh[v.x >> BKT_SHIFT], 1u);
        atomicAdd(&lh[v.y >> BKT_SHIFT], 1u);
        atomicAdd(&lh[v.z >> BKT_SHIFT], 1u);
        atomicAdd(&lh[v.w >> BKT_SHIFT], 1u);
    }
    __syncthreads();
    for (int b = threadIdx.x; b < NBKT; b += 256) hist[b * BINBLK + blockIdx.x] = lh[b];
}

__global__ __launch_bounds__(256) void k_bscan(unsigned* __restrict__ hist,
                                               const unsigned* __restrict__ rowptr) {
    __shared__ unsigned s[256];
    const int b = blockIdx.x, t = threadIdx.x;
    unsigned v = hist[b * BINBLK + t];
    s[t] = v;
    __syncthreads();
    for (int off = 1; off < 256; off <<= 1) {
        unsigned x = s[t];
        unsigned y = (t >= off) ? s[t - off] : 0u;
        __syncthreads();
        s[t] = x + y;
        __syncthreads();
    }
    hist[b * BINBLK + t] = rowptr[b << BKT_SHIFT] + s[t] - v;   // exclusive + bucket base
}

__global__ __launch_bounds__(256) void k_bscat(const int* __restrict__ src,
                                               const int* __restrict__ dst,
                                               const unsigned* __restrict__ hist,
                                               int2* __restrict__ ebuf) {
    __shared__ unsigned lcur[NBKT];
    for (int b = threadIdx.x; b < NBKT; b += 256) lcur[b] = hist[b * BINBLK + blockIdx.x];
    __syncthreads();
    const int4* s4 = (const int4*)src;
    const int4* d4 = (const int4*)dst;
    const int base = blockIdx.x * CHUNK4;
    for (int i = threadIdx.x; i < CHUNK4; i += 256) {
        int4 sv = s4[base + i];
        int4 dv = d4[base + i];
        unsigned p;
        p = atomicAdd(&lcur[dv.x >> BKT_SHIFT], 1u); ebuf[p] = make_int2(sv.x, dv.x);
        p = atomicAdd(&lcur[dv.y >> BKT_SHIFT], 1u); ebuf[p] = make_int2(sv.y, dv.y);
        p = atomicAdd(&lcur[dv.z >> BKT_SHIFT], 1u); ebuf[p] = make_int2(sv.z, dv.z);
        p = atomicAdd(&lcur[dv.w >> BKT_SHIFT], 1u); ebuf[p] = make_int2(sv.w, dv.w);
    }
}

__global__ __launch_bounds__(256) void k_fill3(const int2* __restrict__ ebuf,
                                               const unsigned* __restrict__ rowptr,
                                               int* __restrict__ csr, int N) {
    __shared__ unsigned lcur[1 << BKT_SHIFT];
    const int b = blockIdx.x, t = threadIdx.x;
    if (t < (1 << BKT_SHIFT)) lcur[t] = 0;
    __syncthreads();
    const int n0 = b << BKT_SHIFT;
    const int n1 = min(n0 + (1 << BKT_SHIFT), N);
    const unsigned beg = rowptr[n0];
    const unsigned end = rowptr[n1];
    for (unsigned i = beg + t; i < end; i += 256) {
        int2 e = ebuf[i];
        unsigned pos = rowptr[e.y] + atomicAdd(&lcur[e.y - n0], 1u);
        csr[pos] = e.x;
    }
}

// ---------------- bf16 MFMA GEMM: C[M,128] = A[M,K] @ Wt^T, C bf16 ----------------
// 256 thr = 4 waves; tile 128x128; BK=32; per wave 32 rows x 128 cols (2x8 frags)
template<bool AF32>
__global__ __launch_bounds__(256) void k_gemm_mfma(const void* __restrict__ Ap,
                                                   const unsigned short* __restrict__ Wt,  // [128][K] bf16
                                                   unsigned short* __restrict__ C,
                                                   int M, int K) {
    __shared__ unsigned short As[128][40];   // [row][k] pad 40 (80B stride: 2-way free)
    __shared__ unsigned short Bs[128][40];   // [col][k]
    const int tid = threadIdx.x;
    const int w = tid >> 6;
    const int l = tid & 63;
    const int row0 = blockIdx.x * 128;

    f32x4 acc[2][8];
#pragma unroll
    for (int i = 0; i < 2; i++)
#pragma unroll
        for (int f = 0; f < 8; f++) acc[i][f] = (f32x4){0.f, 0.f, 0.f, 0.f};

    for (int k0 = 0; k0 < K; k0 += 32) {
        // stage A: 128x32 bf16 (fused fp32->bf16 for layer 1)
#pragma unroll
        for (int t = 0; t < 2; t++) {
            int g = tid + t * 256;           // 512 groups of 8 elems
            int r = g >> 2, k8 = (g & 3) * 8;
            int ar = row0 + r;
            u16x8 u = {0, 0, 0, 0, 0, 0, 0, 0};
            if (AF32) {
                if (ar < M) {
                    const float* ap = (const float*)Ap + (size_t)ar * K + k0 + k8;
                    float4 v0 = *(const float4*)ap;
                    float4 v1 = *(const float4*)(ap + 4);
                    u[0] = f2bf(v0.x); u[1] = f2bf(v0.y); u[2] = f2bf(v0.z); u[3] = f2bf(v0.w);
                    u[4] = f2bf(v1.x); u[5] = f2bf(v1.y); u[6] = f2bf(v1.z); u[7] = f2bf(v1.w);
                }
            } else {
                if (ar < M)
                    u = *(const u16x8*)((const unsigned short*)Ap + (size_t)ar * K + k0 + k8);
            }
            *(u16x8*)&As[r][k8] = u;
        }
        // stage B from Wt (already bf16, [n][k])
#pragma unroll
        for (int t = 0; t < 2; t++) {
            int g = tid + t * 256;
            int n = g >> 2, k8 = (g & 3) * 8;
            *(u16x8*)&Bs[n][k8] = *(const u16x8*)&Wt[(size_t)n * K + k0 + k8];
        }
        __syncthreads();

        bf16x8 a0 = *(const bf16x8*)&As[w * 32 + (l & 15)][(l >> 4) * 8];
        bf16x8 a1 = *(const bf16x8*)&As[w * 32 + 16 + (l & 15)][(l >> 4) * 8];
#pragma unroll
        for (int f = 0; f < 8; f++) {
            bf16x8 b = *(const bf16x8*)&Bs[f * 16 + (l & 15)][(l >> 4) * 8];
            acc[0][f] = __builtin_amdgcn_mfma_f32_16x16x32_bf16(a0, b, acc[0][f], 0, 0, 0);
            acc[1][f] = __builtin_amdgcn_mfma_f32_16x16x32_bf16(a1, b, acc[1][f], 0, 0, 0);
        }
        __syncthreads();
    }

    const int colb = l & 15;
    const int rowq = (l >> 4) * 4;
#pragma unroll
    for (int i = 0; i < 2; i++)
#pragma unroll
        for (int f = 0; f < 8; f++) {
            int rbase = row0 + w * 32 + i * 16 + rowq;
#pragma unroll
            for (int r = 0; r < 4; r++) {
                int row = rbase + r;
                if (row < M) C[(size_t)row * 128 + f * 16 + colb] = f2bf(acc[i][f][r]);
            }
        }
}

// ---------------- aggregate: one wave per dst node, bf16 gather, unrolled x8 ----------------
template<int RELU, int OUTBF>
__global__ __launch_bounds__(256) void k_aggregate(const unsigned short* __restrict__ h,
                                                   const int* __restrict__ csr_src,
                                                   const unsigned* __restrict__ rowptr,
                                                   const float* __restrict__ dis,
                                                   const float* __restrict__ bias,
                                                   void* __restrict__ outp, int N) {
    const int wid = (int)((blockIdx.x * (blockDim.x >> 6)) + (threadIdx.x >> 6));
    const int d = __builtin_amdgcn_readfirstlane(wid);   // wave-uniform -> SGPR
    if (d >= N) return;
    const int lane = threadIdx.x & 63;
    const unsigned beg = rowptr[d], end = rowptr[d + 1];
    const float dd = dis[d];
    const unsigned* h1 = reinterpret_cast<const unsigned*>(h);  // 64 dwords/row = 2 bf16 each

    unsigned hv = h1[(size_t)d * 64 + lane];
    float ax = dd * __uint_as_float(hv << 16);           // ch 2*lane
    float ay = dd * __uint_as_float(hv & 0xffff0000u);   // ch 2*lane+1

    unsigned e = beg;
    for (; e + 8 <= end; e += 8) {
        int s[8];
        float w[8];
        unsigned v[8];
#pragma unroll
        for (int u = 0; u < 8; u++) s[u] = csr_src[e + u];
#pragma unroll
        for (int u = 0; u < 8; u++) w[u] = dis[s[u]];
#pragma unroll
        for (int u = 0; u < 8; u++) v[u] = h1[(size_t)s[u] * 64 + lane];
#pragma unroll
        for (int u = 0; u < 8; u++) {
            ax = fmaf(w[u], __uint_as_float(v[u] << 16), ax);
            ay = fmaf(w[u], __uint_as_float(v[u] & 0xffff0000u), ay);
        }
    }
    for (; e < end; e++) {
        int s0 = csr_src[e];
        float w0 = dis[s0];
        unsigned v0 = h1[(size_t)s0 * 64 + lane];
        ax = fmaf(w0, __uint_as_float(v0 << 16), ax);
        ay = fmaf(w0, __uint_as_float(v0 & 0xffff0000u), ay);
    }
    float2 bv = reinterpret_cast<const float2*>(bias)[lane];
    float r0 = fmaf(dd, ax, bv.x);
    float r1 = fmaf(dd, ay, bv.y);
    if (RELU) { r0 = fmaxf(r0, 0.f); r1 = fmaxf(r1, 0.f); }
    if (OUTBF) {
        unsigned pack = (unsigned)f2bf(r0) | ((unsigned)f2bf(r1) << 16);
        reinterpret_cast<unsigned*>(outp)[(size_t)d * 64 + lane] = pack;
    } else {
        reinterpret_cast<float2*>(outp)[(size_t)d * 64 + lane] = make_float2(r0, r1);
    }
}

extern "C" void kernel_launch(void* const* d_in, const int* in_sizes, int n_in,
                              void* d_out, int out_size, void* d_ws, size_t ws_size,
                              hipStream_t stream) {
    const float* x  = (const float*)d_in[0];
    const int*   ei = (const int*)d_in[1];
    const float* W1 = (const float*)d_in[2];
    const float* b1 = (const float*)d_in[3];
    const float* W2 = (const float*)d_in[4];
    const float* b2 = (const float*)d_in[5];
    const int* src = ei;             // edge_index[0]
    const int* dst = ei + N_EDGES;   // edge_index[1]
    float* out = (float*)d_out;

    char* ws = (char*)d_ws;
    unsigned*       deg    = (unsigned*)ws;                         // 400000
    float*          dis    = (float*)(ws + 400000);                 // 400000
    unsigned*       rowptr = (unsigned*)(ws + 800000);              // 400004 (+pad)
    unsigned*       bsum   = (unsigned*)(ws + 1200128);             // 4 KB
    unsigned short* wt1    = (unsigned short*)(ws + 1204224);       // 98304
    unsigned short* wt2    = (unsigned short*)(ws + 1302528);       // 32768
    int*            csr    = (int*)(ws + 1335296);                  // 12.8 MB
    int2*           ebuf   = (int2*)(ws + 14135296);                // 25.6 MB
    unsigned short* hbf    = (unsigned short*)(ws + 39735296);      // 25.6 MB
    unsigned short* abf    = (unsigned short*)(ws + 65335296);      // 25.6 MB region (uses 12.8)
    unsigned*       hist   = (unsigned*)abf;                        // 800 KB alias (dead before L1 agg)

    // ---- degrees + normalization + W conversion ----
    hipMemsetAsync(deg, 0, N_NODES * sizeof(unsigned), stream);
    k_count<<<2048, 256, 0, stream>>>(dst, deg, N_EDGES / 4);
    k_dis<<<(N_NODES + 255) / 256, 256, 0, stream>>>(deg, dis, N_NODES);
    k_wt<<<(IN_CH * 128 + 255) / 256, 256, 0, stream>>>(W1, wt1, IN_CH);
    k_wt<<<(HID * 128 + 255) / 256, 256, 0, stream>>>(W2, wt2, HID);

    // ---- rowptr = exclusive scan of deg ----
    k_scan1<<<SCAN_NBLK, 256, 0, stream>>>(deg, rowptr, bsum, N_NODES);
    k_scan2<<<1, 128, 0, stream>>>(bsum, SCAN_NBLK);
    k_scan3<<<SCAN_NBLK, 256, 0, stream>>>(rowptr, bsum, N_NODES, N_EDGES);

    // ---- CSR build: block-local counting sort by 128-node bucket ----
    k_bhist<<<BINBLK, 256, 0, stream>>>(dst, hist);
    k_bscan<<<NBKT, 256, 0, stream>>>(hist, rowptr);
    k_bscat<<<BINBLK, 256, 0, stream>>>(src, dst, hist, ebuf);
    k_fill3<<<NBKT, 256, 0, stream>>>(ebuf, rowptr, csr, N_NODES);

    // ---- layer 1 ----
    k_gemm_mfma<true><<<(N_NODES + 127) / 128, 256, 0, stream>>>(x, wt1, hbf, N_NODES, IN_CH);
    k_aggregate<1, 1><<<(N_NODES * 64 + 255) / 256, 256, 0, stream>>>(hbf, csr, rowptr, dis, b1, abf, N_NODES);

    // ---- layer 2 ----
    k_gemm_mfma<false><<<(N_NODES + 127) / 128, 256, 0, stream>>>(abf, wt2, hbf, N_NODES, HID);
    k_aggregate<0, 0><<<(N_NODES * 64 + 255) / 256, 256, 0, stream>>>(hbf, csr, rowptr, dis, b2, out, N_NODES);
}

// Round 8
// 426.437 us; speedup vs baseline: 2.2998x; 1.3360x over previous
//
#include <hip/hip_runtime.h>

#define N_NODES 100000
#define N_EDGES 3200000
#define IN_CH   384
#define HID     128
#define BKT_SHIFT 7
#define NBKT ((N_NODES + 127) >> 7)           // 782 buckets x 128 nodes
#define BINBLK 256                            // blocks in binning pass
#define CHUNK4 (N_EDGES / 4 / BINBLK)         // 3125 int4 per block (exact)

typedef __attribute__((ext_vector_type(8))) short          bf16x8;
typedef __attribute__((ext_vector_type(8))) unsigned short u16x8;
typedef __attribute__((ext_vector_type(4))) float          f32x4;

static __device__ __forceinline__ unsigned short f2bf(float f) {
    unsigned u = __float_as_uint(f);
    unsigned r = (u + 0x7fffu + ((u >> 16) & 1u)) >> 16;   // RTN-even
    return (unsigned short)r;
}

// ---------------- W -> transposed bf16: Wt[n][k] ----------------
__global__ void k_wt(const float* __restrict__ W, unsigned short* __restrict__ Wt, int K) {
    int i = blockIdx.x * blockDim.x + threadIdx.x;
    if (i < K * 128) {
        int k = i >> 7, n = i & 127;
        Wt[(size_t)n * K + k] = f2bf(W[i]);
    }
}

// ---------------- counting sort pass 1: per-block LDS bucket histogram ----------------
__global__ __launch_bounds__(256) void k_bhist(const int* __restrict__ dst,
                                               unsigned* __restrict__ hist) {
    __shared__ unsigned lh[NBKT];
    for (int b = threadIdx.x; b < NBKT; b += 256) lh[b] = 0;
    __syncthreads();
    const int4* d4 = (const int4*)dst;
    const int base = blockIdx.x * CHUNK4;
    for (int i = threadIdx.x; i < CHUNK4; i += 256) {
        int4 v = d4[base + i];
        atomicAdd(&lh[v.x >> BKT_SHIFT], 1u);
        atomicAdd(&lh[v.y >> BKT_SHIFT], 1u);
        atomicAdd(&lh[v.z >> BKT_SHIFT], 1u);
        atomicAdd(&lh[v.w >> BKT_SHIFT], 1u);
    }
    __syncthreads();
    for (int b = threadIdx.x; b < NBKT; b += 256) hist[b * BINBLK + blockIdx.x] = lh[b];
}

// pass 2: per-bin exclusive scan over 256 block counts; emit bin totals
__global__ __launch_bounds__(256) void k_bscan(unsigned* __restrict__ hist,
                                               unsigned* __restrict__ bintot) {
    __shared__ unsigned s[256];
    const int b = blockIdx.x, t = threadIdx.x;
    unsigned v = hist[b * BINBLK + t];
    s[t] = v;
    __syncthreads();
    for (int off = 1; off < 256; off <<= 1) {
        unsigned x = s[t];
        unsigned y = (t >= off) ? s[t - off] : 0u;
        __syncthreads();
        s[t] = x + y;
        __syncthreads();
    }
    hist[b * BINBLK + t] = s[t] - v;          // exclusive within bin
    if (t == 255) bintot[b] = s[255];
}

// pass 3: scan 782 bin totals -> binbase (exclusive); binbase[NBKT] = E
__global__ __launch_bounds__(1024) void k_binbase(const unsigned* __restrict__ bintot,
                                                  unsigned* __restrict__ binbase, int nb, int E) {
    __shared__ unsigned s[1024];
    const int t = threadIdx.x;
    unsigned v = (t < nb) ? bintot[t] : 0u;
    s[t] = v;
    __syncthreads();
    for (int off = 1; off < 1024; off <<= 1) {
        unsigned x = s[t];
        unsigned y = (t >= off) ? s[t - off] : 0u;
        __syncthreads();
        s[t] = x + y;
        __syncthreads();
    }
    if (t < nb) binbase[t] = s[t] - v;
    if (t == 0) binbase[nb] = (unsigned)E;
}

// pass 4: scatter packed (loc7|src17) into bucket-grouped ebuf; LDS cursors
__global__ __launch_bounds__(256) void k_bscat(const int* __restrict__ src,
                                               const int* __restrict__ dst,
                                               const unsigned* __restrict__ hist,
                                               const unsigned* __restrict__ binbase,
                                               unsigned* __restrict__ ebuf) {
    __shared__ unsigned lcur[NBKT];
    for (int b = threadIdx.x; b < NBKT; b += 256)
        lcur[b] = binbase[b] + hist[b * BINBLK + blockIdx.x];
    __syncthreads();
    const int4* s4 = (const int4*)src;
    const int4* d4 = (const int4*)dst;
    const int base = blockIdx.x * CHUNK4;
    for (int i = threadIdx.x; i < CHUNK4; i += 256) {
        int4 sv = s4[base + i];
        int4 dv = d4[base + i];
        unsigned p;
        p = atomicAdd(&lcur[dv.x >> BKT_SHIFT], 1u);
        ebuf[p] = ((unsigned)(dv.x & 127) << 17) | (unsigned)sv.x;
        p = atomicAdd(&lcur[dv.y >> BKT_SHIFT], 1u);
        ebuf[p] = ((unsigned)(dv.y & 127) << 17) | (unsigned)sv.y;
        p = atomicAdd(&lcur[dv.z >> BKT_SHIFT], 1u);
        ebuf[p] = ((unsigned)(dv.z & 127) << 17) | (unsigned)sv.z;
        p = atomicAdd(&lcur[dv.w >> BKT_SHIFT], 1u);
        ebuf[p] = ((unsigned)(dv.w & 127) << 17) | (unsigned)sv.w;
    }
}

// pass 5: one block per bucket -> per-node degree, rowptr, dis, csr fill (no k_count/scans)
__global__ __launch_bounds__(256) void k_fill4(const unsigned* __restrict__ ebuf,
                                               const unsigned* __restrict__ binbase,
                                               unsigned* __restrict__ rowptr,
                                               float* __restrict__ dis,
                                               int* __restrict__ csr, int N, int E) {
    __shared__ unsigned lcnt[128];   // per-node count, then scan buffer
    __shared__ unsigned lcur[128];   // per-node fill cursor
    const int b = blockIdx.x, t = threadIdx.x;
    const int n0 = b << BKT_SHIFT;
    const int cnt = min(128, N - n0);
    if (t < 128) lcnt[t] = 0;
    __syncthreads();
    const unsigned beg = binbase[b], end = binbase[b + 1];
    for (unsigned i = beg + t; i < end; i += 256)
        atomicAdd(&lcnt[ebuf[i] >> 17], 1u);
    __syncthreads();
    // 128-wide Hillis-Steele inclusive scan
    unsigned deg_t = (t < 128) ? lcnt[t] : 0u;
    if (t < 128) lcur[t] = deg_t;
    __syncthreads();
    for (int off = 1; off < 128; off <<= 1) {
        unsigned x = 0;
        if (t < 128) {
            x = lcur[t];
            if (t >= off) x += lcur[t - off];
        }
        __syncthreads();
        if (t < 128) lcur[t] = x;
        __syncthreads();
    }
    if (t < cnt) {
        unsigned ex = beg + lcur[t] - deg_t;   // global exclusive offset
        rowptr[n0 + t] = ex;
        dis[n0 + t] = rsqrtf((float)(deg_t + 1u));
        lcur[t] = ex;                           // becomes fill cursor
    }
    if (b == (int)gridDim.x - 1 && t == 0) rowptr[N] = (unsigned)E;
    __syncthreads();
    for (unsigned i = beg + t; i < end; i += 256) {
        unsigned v = ebuf[i];
        unsigned pos = atomicAdd(&lcur[v >> 17], 1u);
        csr[pos] = (int)(v & 0x1FFFFu);
    }
}

// ---------------- bf16 MFMA GEMM: C[M,128] = A[M,K] @ Wt^T, C bf16 ----------------
template<bool AF32>
__global__ __launch_bounds__(256) void k_gemm_mfma(const void* __restrict__ Ap,
                                                   const unsigned short* __restrict__ Wt,  // [128][K] bf16
                                                   unsigned short* __restrict__ C,
                                                   int M, int K) {
    __shared__ unsigned short As[128][40];   // [row][k] pad 40 (80B stride: 2-way free)
    __shared__ unsigned short Bs[128][40];   // [col][k]
    const int tid = threadIdx.x;
    const int w = tid >> 6;
    const int l = tid & 63;
    const int row0 = blockIdx.x * 128;

    f32x4 acc[2][8];
#pragma unroll
    for (int i = 0; i < 2; i++)
#pragma unroll
        for (int f = 0; f < 8; f++) acc[i][f] = (f32x4){0.f, 0.f, 0.f, 0.f};

    for (int k0 = 0; k0 < K; k0 += 32) {
#pragma unroll
        for (int t = 0; t < 2; t++) {
            int g = tid + t * 256;           // 512 groups of 8 elems
            int r = g >> 2, k8 = (g & 3) * 8;
            int ar = row0 + r;
            u16x8 u = {0, 0, 0, 0, 0, 0, 0, 0};
            if (AF32) {
                if (ar < M) {
                    const float* ap = (const float*)Ap + (size_t)ar * K + k0 + k8;
                    float4 v0 = *(const float4*)ap;
                    float4 v1 = *(const float4*)(ap + 4);
                    u[0] = f2bf(v0.x); u[1] = f2bf(v0.y); u[2] = f2bf(v0.z); u[3] = f2bf(v0.w);
                    u[4] = f2bf(v1.x); u[5] = f2bf(v1.y); u[6] = f2bf(v1.z); u[7] = f2bf(v1.w);
                }
            } else {
                if (ar < M)
                    u = *(const u16x8*)((const unsigned short*)Ap + (size_t)ar * K + k0 + k8);
            }
            *(u16x8*)&As[r][k8] = u;
        }
#pragma unroll
        for (int t = 0; t < 2; t++) {
            int g = tid + t * 256;
            int n = g >> 2, k8 = (g & 3) * 8;
            *(u16x8*)&Bs[n][k8] = *(const u16x8*)&Wt[(size_t)n * K + k0 + k8];
        }
        __syncthreads();

        bf16x8 a0 = *(const bf16x8*)&As[w * 32 + (l & 15)][(l >> 4) * 8];
        bf16x8 a1 = *(const bf16x8*)&As[w * 32 + 16 + (l & 15)][(l >> 4) * 8];
#pragma unroll
        for (int f = 0; f < 8; f++) {
            bf16x8 bfr = *(const bf16x8*)&Bs[f * 16 + (l & 15)][(l >> 4) * 8];
            acc[0][f] = __builtin_amdgcn_mfma_f32_16x16x32_bf16(a0, bfr, acc[0][f], 0, 0, 0);
            acc[1][f] = __builtin_amdgcn_mfma_f32_16x16x32_bf16(a1, bfr, acc[1][f], 0, 0, 0);
        }
        __syncthreads();
    }

    const int colb = l & 15;
    const int rowq = (l >> 4) * 4;
#pragma unroll
    for (int i = 0; i < 2; i++)
#pragma unroll
        for (int f = 0; f < 8; f++) {
            int rbase = row0 + w * 32 + i * 16 + rowq;
#pragma unroll
            for (int r = 0; r < 4; r++) {
                int row = rbase + r;
                if (row < M) C[(size_t)row * 128 + f * 16 + colb] = f2bf(acc[i][f][r]);
            }
        }
}

// ---------------- aggregate: one wave per dst node, bf16 gather, unrolled x8 ----------------
template<int RELU, int OUTBF>
__global__ __launch_bounds__(256) void k_aggregate(const unsigned short* __restrict__ h,
                                                   const int* __restrict__ csr_src,
                                                   const unsigned* __restrict__ rowptr,
                                                   const float* __restrict__ dis,
                                                   const float* __restrict__ bias,
                                                   void* __restrict__ outp, int N) {
    const int wid = (int)((blockIdx.x * (blockDim.x >> 6)) + (threadIdx.x >> 6));
    const int d = __builtin_amdgcn_readfirstlane(wid);   // wave-uniform -> SGPR
    if (d >= N) return;
    const int lane = threadIdx.x & 63;
    const unsigned beg = rowptr[d], end = rowptr[d + 1];
    const float dd = dis[d];
    const unsigned* h1 = reinterpret_cast<const unsigned*>(h);  // 64 dwords/row = 2 bf16 each

    unsigned hv = h1[(size_t)d * 64 + lane];
    float ax = dd * __uint_as_float(hv << 16);           // ch 2*lane
    float ay = dd * __uint_as_float(hv & 0xffff0000u);   // ch 2*lane+1

    unsigned e = beg;
    for (; e + 8 <= end; e += 8) {
        int s[8];
        float w[8];
        unsigned v[8];
#pragma unroll
        for (int u = 0; u < 8; u++) s[u] = csr_src[e + u];
#pragma unroll
        for (int u = 0; u < 8; u++) w[u] = dis[s[u]];
#pragma unroll
        for (int u = 0; u < 8; u++) v[u] = h1[(size_t)s[u] * 64 + lane];
#pragma unroll
        for (int u = 0; u < 8; u++) {
            ax = fmaf(w[u], __uint_as_float(v[u] << 16), ax);
            ay = fmaf(w[u], __uint_as_float(v[u] & 0xffff0000u), ay);
        }
    }
    for (; e < end; e++) {
        int s0 = csr_src[e];
        float w0 = dis[s0];
        unsigned v0 = h1[(size_t)s0 * 64 + lane];
        ax = fmaf(w0, __uint_as_float(v0 << 16), ax);
        ay = fmaf(w0, __uint_as_float(v0 & 0xffff0000u), ay);
    }
    float2 bv = reinterpret_cast<const float2*>(bias)[lane];
    float r0 = fmaf(dd, ax, bv.x);
    float r1 = fmaf(dd, ay, bv.y);
    if (RELU) { r0 = fmaxf(r0, 0.f); r1 = fmaxf(r1, 0.f); }
    if (OUTBF) {
        unsigned pack = (unsigned)f2bf(r0) | ((unsigned)f2bf(r1) << 16);
        reinterpret_cast<unsigned*>(outp)[(size_t)d * 64 + lane] = pack;
    } else {
        reinterpret_cast<float2*>(outp)[(size_t)d * 64 + lane] = make_float2(r0, r1);
    }
}

extern "C" void kernel_launch(void* const* d_in, const int* in_sizes, int n_in,
                              void* d_out, int out_size, void* d_ws, size_t ws_size,
                              hipStream_t stream) {
    const float* x  = (const float*)d_in[0];
    const int*   ei = (const int*)d_in[1];
    const float* W1 = (const float*)d_in[2];
    const float* b1 = (const float*)d_in[3];
    const float* W2 = (const float*)d_in[4];
    const float* b2 = (const float*)d_in[5];
    const int* src = ei;             // edge_index[0]
    const int* dst = ei + N_EDGES;   // edge_index[1]
    float* out = (float*)d_out;

    char* ws = (char*)d_ws;
    float*          dis     = (float*)ws;                            // 400000
    unsigned*       rowptr  = (unsigned*)(ws + 400000);              // 400128 (incl [N] + pad)
    unsigned*       bintot  = (unsigned*)(ws + 800128);              // 4096
    unsigned*       binbase = (unsigned*)(ws + 804224);              // 4096 (NBKT+1)
    unsigned short* wt1     = (unsigned short*)(ws + 808320);        // 98304
    unsigned short* wt2     = (unsigned short*)(ws + 906624);        // 32768
    unsigned*       hist    = (unsigned*)(ws + 939392);              // 800768 -> 1740160
    unsigned*       ebuf    = (unsigned*)(ws + 1740288);             // 12.8 MB -> 14540288
    int*            csr     = (int*)(ws + 14540288);                 // 12.8 MB -> 27340288
    unsigned short* hbf     = (unsigned short*)(ws + 27340288);      // 25.6 MB -> 52940288
    unsigned short* abf     = (unsigned short*)(ws + 52940288);      // 25.6 MB

    // ---- weight conversion (independent) ----
    k_wt<<<(IN_CH * 128 + 255) / 256, 256, 0, stream>>>(W1, wt1, IN_CH);
    k_wt<<<(HID * 128 + 255) / 256, 256, 0, stream>>>(W2, wt2, HID);

    // ---- CSR build: counting sort; degrees/rowptr/dis derived in-bucket ----
    k_bhist<<<BINBLK, 256, 0, stream>>>(dst, hist);
    k_bscan<<<NBKT, 256, 0, stream>>>(hist, bintot);
    k_binbase<<<1, 1024, 0, stream>>>(bintot, binbase, NBKT, N_EDGES);
    k_bscat<<<BINBLK, 256, 0, stream>>>(src, dst, hist, binbase, ebuf);
    k_fill4<<<NBKT, 256, 0, stream>>>(ebuf, binbase, rowptr, dis, csr, N_NODES, N_EDGES);

    // ---- layer 1 ----
    k_gemm_mfma<true><<<(N_NODES + 127) / 128, 256, 0, stream>>>(x, wt1, hbf, N_NODES, IN_CH);
    k_aggregate<1, 1><<<(N_NODES * 64 + 255) / 256, 256, 0, stream>>>(hbf, csr, rowptr, dis, b1, abf, N_NODES);

    // ---- layer 2 ----
    k_gemm_mfma<false><<<(N_NODES + 127) / 128, 256, 0, stream>>>(abf, wt2, hbf, N_NODES, HID);
    k_aggregate<0, 0><<<(N_NODES * 64 + 255) / 256, 256, 0, stream>>>(hbf, csr, rowptr, dis, b2, out, N_NODES);
}

// Round 9
// 423.625 us; speedup vs baseline: 2.3150x; 1.0066x over previous
//
#include <hip/hip_runtime.h>

#define N_NODES 100000
#define N_EDGES 3200000
#define IN_CH   384
#define HID     128
#define BKT_SHIFT 7
#define NBKT ((N_NODES + 127) >> 7)           // 782 buckets x 128 nodes
#define BINBLK 128                            // blocks in binning passes
#define BTHREADS 512                          // threads per binning block
#define CHUNK4 (N_EDGES / 4 / BINBLK)         // 6250 int4 per block (exact)

typedef __attribute__((ext_vector_type(8))) short          bf16x8;
typedef __attribute__((ext_vector_type(8))) unsigned short u16x8;
typedef __attribute__((ext_vector_type(4))) float          f32x4;

static __device__ __forceinline__ unsigned short f2bf(float f) {
    unsigned u = __float_as_uint(f);
    unsigned r = (u + 0x7fffu + ((u >> 16) & 1u)) >> 16;   // RTN-even
    return (unsigned short)r;
}

// ---------------- W -> transposed bf16: Wt[n][k] ----------------
__global__ void k_wt(const float* __restrict__ W, unsigned short* __restrict__ Wt, int K) {
    int i = blockIdx.x * blockDim.x + threadIdx.x;
    if (i < K * 128) {
        int k = i >> 7, n = i & 127;
        Wt[(size_t)n * K + k] = f2bf(W[i]);
    }
}

// ---------------- counting sort pass 1: per-block LDS bucket histogram ----------------
__global__ __launch_bounds__(BTHREADS) void k_bhist(const int* __restrict__ dst,
                                                    unsigned* __restrict__ hist) {
    __shared__ unsigned lh[NBKT];
    for (int b = threadIdx.x; b < NBKT; b += BTHREADS) lh[b] = 0;
    __syncthreads();
    const int4* d4 = (const int4*)dst;
    const int base = blockIdx.x * CHUNK4;
    for (int i = threadIdx.x; i < CHUNK4; i += BTHREADS) {
        int4 v = d4[base + i];
        atomicAdd(&lh[v.x >> BKT_SHIFT], 1u);
        atomicAdd(&lh[v.y >> BKT_SHIFT], 1u);
        atomicAdd(&lh[v.z >> BKT_SHIFT], 1u);
        atomicAdd(&lh[v.w >> BKT_SHIFT], 1u);
    }
    __syncthreads();
    for (int b = threadIdx.x; b < NBKT; b += BTHREADS) hist[b * BINBLK + blockIdx.x] = lh[b];
}

// pass 2: per-bin exclusive scan over BINBLK block counts; emit bin totals
__global__ __launch_bounds__(BINBLK) void k_bscan(unsigned* __restrict__ hist,
                                                  unsigned* __restrict__ bintot) {
    __shared__ unsigned s[BINBLK];
    const int b = blockIdx.x, t = threadIdx.x;
    unsigned v = hist[b * BINBLK + t];
    s[t] = v;
    __syncthreads();
    for (int off = 1; off < BINBLK; off <<= 1) {
        unsigned x = s[t];
        unsigned y = (t >= off) ? s[t - off] : 0u;
        __syncthreads();
        s[t] = x + y;
        __syncthreads();
    }
    hist[b * BINBLK + t] = s[t] - v;          // exclusive within bin
    if (t == BINBLK - 1) bintot[b] = s[BINBLK - 1];
}

// pass 3: scan 782 bin totals -> binbase (exclusive); binbase[NBKT] = E
__global__ __launch_bounds__(1024) void k_binbase(const unsigned* __restrict__ bintot,
                                                  unsigned* __restrict__ binbase, int nb, int E) {
    __shared__ unsigned s[1024];
    const int t = threadIdx.x;
    unsigned v = (t < nb) ? bintot[t] : 0u;
    s[t] = v;
    __syncthreads();
    for (int off = 1; off < 1024; off <<= 1) {
        unsigned x = s[t];
        unsigned y = (t >= off) ? s[t - off] : 0u;
        __syncthreads();
        s[t] = x + y;
        __syncthreads();
    }
    if (t < nb) binbase[t] = s[t] - v;
    if (t == 0) binbase[nb] = (unsigned)E;
}

// pass 4: scatter packed (loc7|src17) into bucket-grouped ebuf; LDS cursors
__global__ __launch_bounds__(BTHREADS) void k_bscat(const int* __restrict__ src,
                                                    const int* __restrict__ dst,
                                                    const unsigned* __restrict__ hist,
                                                    const unsigned* __restrict__ binbase,
                                                    unsigned* __restrict__ ebuf) {
    __shared__ unsigned lcur[NBKT];
    for (int b = threadIdx.x; b < NBKT; b += BTHREADS)
        lcur[b] = binbase[b] + hist[b * BINBLK + blockIdx.x];
    __syncthreads();
    const int4* s4 = (const int4*)src;
    const int4* d4 = (const int4*)dst;
    const int base = blockIdx.x * CHUNK4;
    for (int i = threadIdx.x; i < CHUNK4; i += BTHREADS) {
        int4 sv = s4[base + i];
        int4 dv = d4[base + i];
        unsigned p;
        p = atomicAdd(&lcur[dv.x >> BKT_SHIFT], 1u);
        ebuf[p] = ((unsigned)(dv.x & 127) << 17) | (unsigned)sv.x;
        p = atomicAdd(&lcur[dv.y >> BKT_SHIFT], 1u);
        ebuf[p] = ((unsigned)(dv.y & 127) << 17) | (unsigned)sv.y;
        p = atomicAdd(&lcur[dv.z >> BKT_SHIFT], 1u);
        ebuf[p] = ((unsigned)(dv.z & 127) << 17) | (unsigned)sv.z;
        p = atomicAdd(&lcur[dv.w >> BKT_SHIFT], 1u);
        ebuf[p] = ((unsigned)(dv.w & 127) << 17) | (unsigned)sv.w;
    }
}

// pass 5: one block per bucket -> per-node degree, rowptr, dis, csr fill
__global__ __launch_bounds__(256) void k_fill4(const unsigned* __restrict__ ebuf,
                                               const unsigned* __restrict__ binbase,
                                               unsigned* __restrict__ rowptr,
                                               float* __restrict__ dis,
                                               int* __restrict__ csr, int N, int E) {
    __shared__ unsigned lcnt[128];   // per-node count
    __shared__ unsigned lcur[128];   // scan buffer, then fill cursor
    const int b = blockIdx.x, t = threadIdx.x;
    const int n0 = b << BKT_SHIFT;
    const int cnt = min(128, N - n0);
    if (t < 128) lcnt[t] = 0;
    __syncthreads();
    const unsigned beg = binbase[b], end = binbase[b + 1];
    for (unsigned i = beg + t; i < end; i += 256)
        atomicAdd(&lcnt[ebuf[i] >> 17], 1u);
    __syncthreads();
    unsigned deg_t = (t < 128) ? lcnt[t] : 0u;
    if (t < 128) lcur[t] = deg_t;
    __syncthreads();
    for (int off = 1; off < 128; off <<= 1) {
        unsigned x = 0;
        if (t < 128) {
            x = lcur[t];
            if (t >= off) x += lcur[t - off];
        }
        __syncthreads();
        if (t < 128) lcur[t] = x;
        __syncthreads();
    }
    if (t < cnt) {
        unsigned ex = beg + lcur[t] - deg_t;   // global exclusive offset
        rowptr[n0 + t] = ex;
        dis[n0 + t] = rsqrtf((float)(deg_t + 1u));
        lcur[t] = ex;                           // becomes fill cursor
    }
    if (b == (int)gridDim.x - 1 && t == 0) rowptr[N] = (unsigned)E;
    __syncthreads();
    for (unsigned i = beg + t; i < end; i += 256) {
        unsigned v = ebuf[i];
        unsigned pos = atomicAdd(&lcur[v >> 17], 1u);
        csr[pos] = (int)(v & 0x1FFFFu);
    }
}

// ---------------- bf16 MFMA GEMM: C[M,128] = A[M,K] @ Wt^T, C bf16 ----------------
template<bool AF32>
__global__ __launch_bounds__(256) void k_gemm_mfma(const void* __restrict__ Ap,
                                                   const unsigned short* __restrict__ Wt,  // [128][K] bf16
                                                   unsigned short* __restrict__ C,
                                                   int M, int K) {
    __shared__ unsigned short As[128][40];   // [row][k] pad 40 (80B stride: 2-way free)
    __shared__ unsigned short Bs[128][40];   // [col][k]
    const int tid = threadIdx.x;
    const int w = tid >> 6;
    const int l = tid & 63;
    const int row0 = blockIdx.x * 128;

    f32x4 acc[2][8];
#pragma unroll
    for (int i = 0; i < 2; i++)
#pragma unroll
        for (int f = 0; f < 8; f++) acc[i][f] = (f32x4){0.f, 0.f, 0.f, 0.f};

    for (int k0 = 0; k0 < K; k0 += 32) {
#pragma unroll
        for (int t = 0; t < 2; t++) {
            int g = tid + t * 256;           // 512 groups of 8 elems
            int r = g >> 2, k8 = (g & 3) * 8;
            int ar = row0 + r;
            u16x8 u = {0, 0, 0, 0, 0, 0, 0, 0};
            if (AF32) {
                if (ar < M) {
                    const float* ap = (const float*)Ap + (size_t)ar * K + k0 + k8;
                    float4 v0 = *(const float4*)ap;
                    float4 v1 = *(const float4*)(ap + 4);
                    u[0] = f2bf(v0.x); u[1] = f2bf(v0.y); u[2] = f2bf(v0.z); u[3] = f2bf(v0.w);
                    u[4] = f2bf(v1.x); u[5] = f2bf(v1.y); u[6] = f2bf(v1.z); u[7] = f2bf(v1.w);
                }
            } else {
                if (ar < M)
                    u = *(const u16x8*)((const unsigned short*)Ap + (size_t)ar * K + k0 + k8);
            }
            *(u16x8*)&As[r][k8] = u;
        }
#pragma unroll
        for (int t = 0; t < 2; t++) {
            int g = tid + t * 256;
            int n = g >> 2, k8 = (g & 3) * 8;
            *(u16x8*)&Bs[n][k8] = *(const u16x8*)&Wt[(size_t)n * K + k0 + k8];
        }
        __syncthreads();

        bf16x8 a0 = *(const bf16x8*)&As[w * 32 + (l & 15)][(l >> 4) * 8];
        bf16x8 a1 = *(const bf16x8*)&As[w * 32 + 16 + (l & 15)][(l >> 4) * 8];
#pragma unroll
        for (int f = 0; f < 8; f++) {
            bf16x8 bfr = *(const bf16x8*)&Bs[f * 16 + (l & 15)][(l >> 4) * 8];
            acc[0][f] = __builtin_amdgcn_mfma_f32_16x16x32_bf16(a0, bfr, acc[0][f], 0, 0, 0);
            acc[1][f] = __builtin_amdgcn_mfma_f32_16x16x32_bf16(a1, bfr, acc[1][f], 0, 0, 0);
        }
        __syncthreads();
    }

    const int colb = l & 15;
    const int rowq = (l >> 4) * 4;
#pragma unroll
    for (int i = 0; i < 2; i++)
#pragma unroll
        for (int f = 0; f < 8; f++) {
            int rbase = row0 + w * 32 + i * 16 + rowq;
#pragma unroll
            for (int r = 0; r < 4; r++) {
                int row = rbase + r;
                if (row < M) C[(size_t)row * 128 + f * 16 + colb] = f2bf(acc[i][f][r]);
            }
        }
}

// ---------------- aggregate: one wave per dst node, bf16 gather, unrolled x16 ----------------
template<int RELU, int OUTBF>
__global__ __launch_bounds__(256) void k_aggregate(const unsigned short* __restrict__ h,
                                                   const int* __restrict__ csr_src,
                                                   const unsigned* __restrict__ rowptr,
                                                   const float* __restrict__ dis,
                                                   const float* __restrict__ bias,
                                                   void* __restrict__ outp, int N) {
    const int wid = (int)((blockIdx.x * (blockDim.x >> 6)) + (threadIdx.x >> 6));
    const int d = __builtin_amdgcn_readfirstlane(wid);   // wave-uniform -> SGPR
    if (d >= N) return;
    const int lane = threadIdx.x & 63;
    const unsigned beg = rowptr[d], end = rowptr[d + 1];
    const float dd = dis[d];
    const unsigned* h1 = reinterpret_cast<const unsigned*>(h);  // 64 dwords/row = 2 bf16 each

    unsigned hv = h1[(size_t)d * 64 + lane];
    float ax = dd * __uint_as_float(hv << 16);           // ch 2*lane
    float ay = dd * __uint_as_float(hv & 0xffff0000u);   // ch 2*lane+1

    unsigned e = beg;
    for (; e + 16 <= end; e += 16) {
        int s[16];
        float w[16];
        unsigned v[16];
#pragma unroll
        for (int u = 0; u < 16; u++) s[u] = csr_src[e + u];
#pragma unroll
        for (int u = 0; u < 16; u++) w[u] = dis[s[u]];
#pragma unroll
        for (int u = 0; u < 16; u++) v[u] = h1[(size_t)s[u] * 64 + lane];
#pragma unroll
        for (int u = 0; u < 16; u++) {
            ax = fmaf(w[u], __uint_as_float(v[u] << 16), ax);
            ay = fmaf(w[u], __uint_as_float(v[u] & 0xffff0000u), ay);
        }
    }
    if (e + 8 <= end) {
        int s[8];
        float w[8];
        unsigned v[8];
#pragma unroll
        for (int u = 0; u < 8; u++) s[u] = csr_src[e + u];
#pragma unroll
        for (int u = 0; u < 8; u++) w[u] = dis[s[u]];
#pragma unroll
        for (int u = 0; u < 8; u++) v[u] = h1[(size_t)s[u] * 64 + lane];
#pragma unroll
        for (int u = 0; u < 8; u++) {
            ax = fmaf(w[u], __uint_as_float(v[u] << 16), ax);
            ay = fmaf(w[u], __uint_as_float(v[u] & 0xffff0000u), ay);
        }
        e += 8;
    }
    for (; e < end; e++) {
        int s0 = csr_src[e];
        float w0 = dis[s0];
        unsigned v0 = h1[(size_t)s0 * 64 + lane];
        ax = fmaf(w0, __uint_as_float(v0 << 16), ax);
        ay = fmaf(w0, __uint_as_float(v0 & 0xffff0000u), ay);
    }
    float2 bv = reinterpret_cast<const float2*>(bias)[lane];
    float r0 = fmaf(dd, ax, bv.x);
    float r1 = fmaf(dd, ay, bv.y);
    if (RELU) { r0 = fmaxf(r0, 0.f); r1 = fmaxf(r1, 0.f); }
    if (OUTBF) {
        unsigned pack = (unsigned)f2bf(r0) | ((unsigned)f2bf(r1) << 16);
        reinterpret_cast<unsigned*>(outp)[(size_t)d * 64 + lane] = pack;
    } else {
        reinterpret_cast<float2*>(outp)[(size_t)d * 64 + lane] = make_float2(r0, r1);
    }
}

extern "C" void kernel_launch(void* const* d_in, const int* in_sizes, int n_in,
                              void* d_out, int out_size, void* d_ws, size_t ws_size,
                              hipStream_t stream) {
    const float* x  = (const float*)d_in[0];
    const int*   ei = (const int*)d_in[1];
    const float* W1 = (const float*)d_in[2];
    const float* b1 = (const float*)d_in[3];
    const float* W2 = (const float*)d_in[4];
    const float* b2 = (const float*)d_in[5];
    const int* src = ei;             // edge_index[0]
    const int* dst = ei + N_EDGES;   // edge_index[1]
    float* out = (float*)d_out;

    char* ws = (char*)d_ws;
    float*          dis     = (float*)ws;                            // 400000
    unsigned*       rowptr  = (unsigned*)(ws + 400000);              // 400128 (incl [N] + pad)
    unsigned*       bintot  = (unsigned*)(ws + 800128);              // 4096
    unsigned*       binbase = (unsigned*)(ws + 804224);              // 4096 (NBKT+1)
    unsigned short* wt1     = (unsigned short*)(ws + 808320);        // 98304
    unsigned short* wt2     = (unsigned short*)(ws + 906624);        // 32768
    unsigned*       hist    = (unsigned*)(ws + 939392);              // NBKT*BINBLK*4 = 400384 -> pad 400640
    unsigned*       ebuf    = (unsigned*)(ws + 1340032);             // 12.8 MB
    int*            csr     = (int*)(ws + 14140032);                 // 12.8 MB
    unsigned short* hbf     = (unsigned short*)(ws + 26940032);      // 25.6 MB
    unsigned short* abf     = (unsigned short*)(ws + 52540032);      // 25.6 MB

    // ---- weight conversion (independent) ----
    k_wt<<<(IN_CH * 128 + 255) / 256, 256, 0, stream>>>(W1, wt1, IN_CH);
    k_wt<<<(HID * 128 + 255) / 256, 256, 0, stream>>>(W2, wt2, HID);

    // ---- CSR build: counting sort; degrees/rowptr/dis derived in-bucket ----
    k_bhist<<<BINBLK, BTHREADS, 0, stream>>>(dst, hist);
    k_bscan<<<NBKT, BINBLK, 0, stream>>>(hist, bintot);
    k_binbase<<<1, 1024, 0, stream>>>(bintot, binbase, NBKT, N_EDGES);
    k_bscat<<<BINBLK, BTHREADS, 0, stream>>>(src, dst, hist, binbase, ebuf);
    k_fill4<<<NBKT, 256, 0, stream>>>(ebuf, binbase, rowptr, dis, csr, N_NODES, N_EDGES);

    // ---- layer 1 ----
    k_gemm_mfma<true><<<(N_NODES + 127) / 128, 256, 0, stream>>>(x, wt1, hbf, N_NODES, IN_CH);
    k_aggregate<1, 1><<<(N_NODES * 64 + 255) / 256, 256, 0, stream>>>(hbf, csr, rowptr, dis, b1, abf, N_NODES);

    // ---- layer 2 ----
    k_gemm_mfma<false><<<(N_NODES + 127) / 128, 256, 0, stream>>>(abf, wt2, hbf, N_NODES, HID);
    k_aggregate<0, 0><<<(N_NODES * 64 + 255) / 256, 256, 0, stream>>>(hbf, csr, rowptr, dis, b2, out, N_NODES);
}